// Round 1
// baseline (108.342 us; speedup 1.0000x reference)
//
#include <hip/hip_runtime.h>

// Fused GNN actor: proj -> GraphConv1+tanh -> GraphConv2+tanh -> heads(loc, softplus scale)
// Block = 256 threads (4 waves) = 16 graphs. All intermediates in LDS (bf16, XOR-swizzled).
// Conv GEMMs via v_mfma_f32_16x16x32_bf16; per-wave N-slice of 16 cols.
// Weights pre-packed to d_ws in B-fragment layout by a tiny pack kernel.

typedef __attribute__((ext_vector_type(8))) short bf16x8;
typedef __attribute__((ext_vector_type(4))) float f32x4;

#define SOFTPLUS_BIAS 0.5413248546129181f

// ---- LDS byte offsets ----
#define LDS_H    0        // 144 rows x 128B bf16, swizzled
#define LDS_S    18432    // 16 rows x 128B bf16, swizzled (per-graph joint sums)
#define LDS_REL  20480    // 32 rows x 272B fp32[68] (rel GEMM out, bias included)
#define LDS_W    29184    // 16KB: [W_rel 8KB | W_root 8KB] current layer, B-frag packed
#define LDS_HW   45568    // 2KB heads B-frag
#define LDS_X    47616    // 1584 fp32 staged x chunk
#define LDS_SZ   53952

__device__ __forceinline__ int swz(int row) { return ((row ^ (row >> 3)) & 7) << 4; }

__device__ __forceinline__ unsigned short f2bf(float f) {  // RNE, finite inputs only
  union { float f; unsigned int i; } v; v.f = f;
  unsigned int lsb = (v.i >> 16) & 1u;
  return (unsigned short)((v.i + 0x7fffu + lsb) >> 16);
}
__device__ __forceinline__ float bf2f(unsigned short u) {
  union { unsigned int i; float f; } v; v.i = ((unsigned int)u) << 16; return v.f;
}
__device__ __forceinline__ float fast_tanh(float x) {
  float e = __expf(2.0f * x);                       // inf-safe: e=inf -> rcp=0 -> 1
  return 1.0f - 2.0f * __builtin_amdgcn_rcpf(e + 1.0f);
}

// ---- pack kernel: weights -> d_ws as bf16 B-fragments ----
// ws elems: [0,4096) Wrel1 | [4096,8192) Wroot1 | [8192,12288) Wrel2 |
//           [12288,16384) Wroot2 | [16384,17408) heads
// Conv frag addr: ((ks*4 + ntile)*64 + lane)*8 + e ; value = W[k][col],
//   k = (lane>>4)*8 + e + 32*ks, col = ntile*16 + (lane&15).
// Heads frag: ((ks)*64+lane)*8+e ; col c=lane&15 -> j=c>>1,o=c&1 ; B[k][c]=Wh[j][k][o].
__global__ void pack_weights(const float* __restrict__ Wrel1, const float* __restrict__ Wroot1,
                             const float* __restrict__ Wrel2, const float* __restrict__ Wroot2,
                             const float* __restrict__ Wheads, unsigned short* __restrict__ ws) {
  int id = blockIdx.x * 256 + threadIdx.x;
  if (id < 16384) {
    const float* W = (id < 4096) ? Wrel1 : (id < 8192) ? Wroot1 : (id < 12288) ? Wrel2 : Wroot2;
    int m = id & 4095;
    int e = m & 7, lane = (m >> 3) & 63, nt = (m >> 9) & 3, ks = m >> 11;
    int k = ((lane >> 4) << 3) + e + (ks << 5);
    int col = (nt << 4) + (lane & 15);
    ws[id] = f2bf(W[k * 64 + col]);
  } else if (id < 17408) {
    int m = id - 16384;
    int e = m & 7, lane = (m >> 3) & 63, ks = m >> 9;
    int k = ((lane >> 4) << 3) + e + (ks << 5);
    int c = lane & 15, j = c >> 1, o = c & 1;
    ws[id] = f2bf(Wheads[(j * 64 + k) * 2 + o]);
  }
}

__launch_bounds__(256, 2)
__global__ void actor_main(const float* __restrict__ x,
                           const float* __restrict__ Wj_g, const float* __restrict__ bj_g,
                           const float* __restrict__ Wt_g, const float* __restrict__ bt_g,
                           const float* __restrict__ brel1_g, const float* __restrict__ brel2_g,
                           const float* __restrict__ bh_g,
                           const unsigned short* __restrict__ wsw,
                           float* __restrict__ out) {
  __shared__ __align__(16) unsigned char smem[LDS_SZ];
  const int t = threadIdx.x;
  const int lane = t & 63;
  const int w = t >> 6;                 // wave id = N-tile for conv GEMMs
  const int gbase = blockIdx.x << 4;    // 16 graphs per block
  const int ks16 = (lane >> 4) << 4;    // A-frag k-slice byte offset {0,16,32,48}

  // ---- stage x chunk, layer-1 weights, heads frag ----
  {
    const float4* xg = reinterpret_cast<const float4*>(x + (size_t)gbase * 99);
    float4* xl = reinterpret_cast<float4*>(smem + LDS_X);
    xl[t] = xg[t];                                   // 256 of 396
    if (t + 256 < 396) xl[t + 256] = xg[t + 256];
    const bf16x8* wsrc = reinterpret_cast<const bf16x8*>(wsw);
    bf16x8* wdst = reinterpret_cast<bf16x8*>(smem + LDS_W);
#pragma unroll
    for (int i = 0; i < 4; i++) wdst[t + 256 * i] = wsrc[t + 256 * i];
    const bf16x8* hsrc = reinterpret_cast<const bf16x8*>(wsw + 16384);
    bf16x8* hdst = reinterpret_cast<bf16x8*>(smem + LDS_HW);
    if (t < 128) hdst[t] = hsrc[t];
  }
  // per-thread constants (thread's out-dim d = lane is fixed for VALU passes)
  float Wtr[11];
#pragma unroll
  for (int k = 0; k < 11; k++) Wtr[k] = Wt_g[k * 64 + lane];
  const float btr = bt_g[lane];
  const float Wj0 = Wj_g[lane], Wj1 = Wj_g[64 + lane], bjr = bj_g[lane];
  const int relc = (lane & 15) + (w << 4);           // this wave's output column
  const float brel1 = brel1_g[relc], brel2 = brel2_g[relc];
  __syncthreads();

  // ---- input projection (VALU, weights in regs, x broadcast from LDS) ----
  const float* xl = reinterpret_cast<const float*>(smem + LDS_X);
#pragma unroll
  for (int it = 0; it < 4; it++) {                   // torso rows
    int g = (t >> 6) + (it << 2);
    float acc = btr;
#pragma unroll
    for (int k = 0; k < 11; k++) acc += xl[g * 99 + k] * Wtr[k];
    int row = 9 * g;
    *reinterpret_cast<unsigned short*>(smem + LDS_H + row * 128 + ((2 * lane) ^ swz(row))) = f2bf(acc);
  }
#pragma unroll
  for (int it = 0; it < 32; it++) {                  // joint rows
    int jr = (t >> 6) + (it << 2);
    int g = jr >> 3, j = jr & 7;
    int xb = g * 99 + (1 + j) * 11;
    float acc = bjr + xl[xb] * Wj0 + xl[xb + 1] * Wj1;
    int row = 9 * g + 1 + j;
    *reinterpret_cast<unsigned short*>(smem + LDS_H + row * 128 + ((2 * lane) ^ swz(row))) = f2bf(acc);
  }
  __syncthreads();

  float* RELf = reinterpret_cast<float*>(smem + LDS_REL);

#pragma unroll
  for (int layer = 0; layer < 2; layer++) {
    const float brel = (layer == 0) ? brel1 : brel2;

    // ---- S pass: S[g][d] = sum_j H[9g+1+j][d] (b32 = 2 dims per thread) ----
    {
      int d2 = t & 31;
#pragma unroll
      for (int it = 0; it < 2; it++) {
        int g = (t >> 5) + (it << 3);
        float s0 = 0.f, s1 = 0.f;
#pragma unroll
        for (int j = 0; j < 8; j++) {
          int row = 9 * g + 1 + j;
          unsigned int p = *reinterpret_cast<const unsigned int*>(
              smem + LDS_H + row * 128 + ((4 * d2) ^ swz(row)));
          s0 += bf2f((unsigned short)(p & 0xffffu));
          s1 += bf2f((unsigned short)(p >> 16));
        }
        unsigned int packed = ((unsigned int)f2bf(s1) << 16) | (unsigned int)f2bf(s0);
        *reinterpret_cast<unsigned int*>(smem + LDS_S + g * 128 + ((4 * d2) ^ swz(g))) = packed;
      }
    }
    __syncthreads();

    // ---- GEMMs (read H/S/W; no H writes until after barrier) ----
    const unsigned char* wrel = smem + LDS_W;
    const unsigned char* wroot = smem + LDS_W + 8192;
    bf16x8 bRel0  = *reinterpret_cast<const bf16x8*>(wrel  + ((0 * 4 + w) * 64 + lane) * 16);
    bf16x8 bRel1  = *reinterpret_cast<const bf16x8*>(wrel  + ((1 * 4 + w) * 64 + lane) * 16);
    bf16x8 bRoot0 = *reinterpret_cast<const bf16x8*>(wroot + ((0 * 4 + w) * 64 + lane) * 16);
    bf16x8 bRoot1 = *reinterpret_cast<const bf16x8*>(wroot + ((1 * 4 + w) * 64 + lane) * 16);

    // REL: rows 2g=torso(g), 2g+1=S(g); bias in C-init; -> LDS fp32 (own cols only)
#pragma unroll
    for (int tt = 0; tt < 2; tt++) {
      int r = (lane & 15) + (tt << 4);
      int g = r >> 1;
      int arow = (r & 1) ? g : 9 * g;
      const unsigned char* abase = (r & 1) ? (smem + LDS_S) : (smem + LDS_H);
      int sw = swz(arow);
      bf16x8 a0 = *reinterpret_cast<const bf16x8*>(abase + arow * 128 + (ks16 ^ sw));
      bf16x8 a1 = *reinterpret_cast<const bf16x8*>(abase + arow * 128 + ((ks16 + 64) ^ sw));
      f32x4 acc = {brel, brel, brel, brel};
      acc = __builtin_amdgcn_mfma_f32_16x16x32_bf16(a0, bRel0, acc, 0, 0, 0);
      acc = __builtin_amdgcn_mfma_f32_16x16x32_bf16(a1, bRel1, acc, 0, 0, 0);
#pragma unroll
      for (int i = 0; i < 4; i++) {
        int rr = (tt << 4) + ((lane >> 4) << 2) + i;
        RELf[rr * 68 + relc] = acc[i];
      }
    }
    // ROOT: 9 M-tiles over all 144 node rows
    f32x4 accR[9];
#pragma unroll
    for (int m = 0; m < 9; m++) {
      int arow = (m << 4) + (lane & 15);
      int sw = swz(arow);
      bf16x8 a0 = *reinterpret_cast<const bf16x8*>(smem + LDS_H + arow * 128 + (ks16 ^ sw));
      bf16x8 a1 = *reinterpret_cast<const bf16x8*>(smem + LDS_H + arow * 128 + ((ks16 + 64) ^ sw));
      f32x4 z = {0.f, 0.f, 0.f, 0.f};
      z = __builtin_amdgcn_mfma_f32_16x16x32_bf16(a0, bRoot0, z, 0, 0, 0);
      accR[m] = __builtin_amdgcn_mfma_f32_16x16x32_bf16(a1, bRoot1, z, 0, 0, 0);
    }
    __syncthreads();   // all H reads done -> safe to overwrite H; RELf visible (own wave)

    // stage next layer's weights (consumed only after 2 more barriers)
    if (layer == 0) {
      const bf16x8* wsrc2 = reinterpret_cast<const bf16x8*>(wsw + 8192);
      bf16x8* wdst = reinterpret_cast<bf16x8*>(smem + LDS_W);
#pragma unroll
      for (int i = 0; i < 4; i++) wdst[t + 256 * i] = wsrc2[t + 256 * i];
    }

    // ---- combine + tanh + write H in place (own 16-col slice) ----
#pragma unroll
    for (int m = 0; m < 9; m++) {
#pragma unroll
      for (int i = 0; i < 4; i++) {
        int r = (m << 4) + ((lane >> 4) << 2) + i;
        int g = (57 * r) >> 9;                        // exact r/9 for r<472
        int node = r - 9 * g;
        int relrow = (g << 1) + (node == 0 ? 1 : 0);  // torso uses S@Wrel, joints use T@Wrel
        float v = accR[m][i] + RELf[relrow * 68 + relc];
        float th = fast_tanh(v);
        *reinterpret_cast<unsigned short*>(smem + LDS_H + r * 128 + ((2 * relc) ^ swz(r))) = f2bf(th);
      }
    }
    __syncthreads();
  }

  // ---- heads: packed B [64,16], cols = (j,o); predicated scatter + softplus ----
  {
    const unsigned char* hw = smem + LDS_HW;
    bf16x8 hb0 = *reinterpret_cast<const bf16x8*>(hw + (0 * 64 + lane) * 16);
    bf16x8 hb1 = *reinterpret_cast<const bf16x8*>(hw + (1 * 64 + lane) * 16);
    int c = lane & 15;
#pragma unroll
    for (int u = 0; u < 2; u++) {
      int tt = (w << 1) + u;
      int jr = (tt << 4) + (lane & 15);
      int arow = 9 * (jr >> 3) + 1 + (jr & 7);
      int sw = swz(arow);
      bf16x8 a0 = *reinterpret_cast<const bf16x8*>(smem + LDS_H + arow * 128 + (ks16 ^ sw));
      bf16x8 a1 = *reinterpret_cast<const bf16x8*>(smem + LDS_H + arow * 128 + ((ks16 + 64) ^ sw));
      f32x4 z = {0.f, 0.f, 0.f, 0.f};
      z = __builtin_amdgcn_mfma_f32_16x16x32_bf16(a0, hb0, z, 0, 0, 0);
      z = __builtin_amdgcn_mfma_f32_16x16x32_bf16(a1, hb1, z, 0, 0, 0);
#pragma unroll
      for (int i = 0; i < 4; i++) {
        int r = (tt << 4) + ((lane >> 4) << 2) + i;   // = jr index of this D row
        int gg = r >> 3, j2 = r & 7;
        if (c == 2 * j2) {
          out[(size_t)(gbase + gg) * 8 + j2] = z[i] + bh_g[2 * j2];
        } else if (c == 2 * j2 + 1) {
          float zz = z[i] + bh_g[2 * j2 + 1] + SOFTPLUS_BIAS;
          float sp = (zz > 20.0f) ? zz : __logf(1.0f + __expf(zz));
          out[524288 + (size_t)(gbase + gg) * 8 + j2] = sp;
        }
      }
    }
  }
}

extern "C" void kernel_launch(void* const* d_in, const int* in_sizes, int n_in,
                              void* d_out, int out_size, void* d_ws, size_t ws_size,
                              hipStream_t stream) {
  const float* x      = (const float*)d_in[0];
  // d_in[1] = edge_index (star structure is hardcoded)
  const float* Wj     = (const float*)d_in[2];
  const float* bj     = (const float*)d_in[3];
  const float* Wt     = (const float*)d_in[4];
  const float* bt     = (const float*)d_in[5];
  const float* Wrel1  = (const float*)d_in[6];
  const float* brel1  = (const float*)d_in[7];
  const float* Wroot1 = (const float*)d_in[8];
  const float* Wrel2  = (const float*)d_in[9];
  const float* brel2  = (const float*)d_in[10];
  const float* Wroot2 = (const float*)d_in[11];
  const float* Wheads = (const float*)d_in[12];
  const float* bh     = (const float*)d_in[13];
  unsigned short* ws16 = (unsigned short*)d_ws;
  float* out = (float*)d_out;

  hipLaunchKernelGGL(pack_weights, dim3(68), dim3(256), 0, stream,
                     Wrel1, Wroot1, Wrel2, Wroot2, Wheads, ws16);
  hipLaunchKernelGGL(actor_main, dim3(4096), dim3(256), 0, stream,
                     x, Wj, bj, Wt, bt, brel1, brel2, bh, ws16, out);
}

// Round 2
// 69.843 us; speedup vs baseline: 1.5512x; 1.5512x over previous
//
#include <hip/hip_runtime.h>

// Fused GNN actor: proj -> GraphConv1+tanh -> GraphConv2+tanh -> heads(loc, softplus scale)
// Block = 256 threads (4 waves) = 16 graphs. H in LDS bf16, swizzle (row&7)<<4.
// Per M-tile: acc = AGG@Wrel + H@Wroot + brel, all four MFMAs chained into one f32x4.
// AGG operand gathered per-lane from S-row (torso rows) / torso-H-row (joint rows).

typedef __attribute__((ext_vector_type(8))) short bf16x8;
typedef __attribute__((ext_vector_type(4))) float f32x4;

#define SOFTPLUS_BIAS 0.5413248546129181f

// ---- LDS byte offsets ----
#define LDS_H   0        // 144 rows x 128B bf16, swizzled
#define LDS_S   18432    // 16 rows x 128B bf16, swizzled (per-graph joint sums)
#define LDS_HW  20480    // 2KB heads B-frag
#define LDS_W   22528    // 16KB current layer [W_rel | W_root] B-frag packed; x overlaid pre-proj
#define LDS_SZ  38912

__device__ __forceinline__ unsigned int cvtpk(float lo, float hi) {
  unsigned int r;
  asm("v_cvt_pk_bf16_f32 %0, %1, %2" : "=v"(r) : "v"(lo), "v"(hi));
  return r;
}
__device__ __forceinline__ float asf(unsigned int u) {
  union { unsigned int i; float f; } v; v.i = u; return v.f;
}
__device__ __forceinline__ unsigned short f2bf(float f) {  // RNE, pack kernel only
  union { float f; unsigned int i; } v; v.f = f;
  unsigned int lsb = (v.i >> 16) & 1u;
  return (unsigned short)((v.i + 0x7fffu + lsb) >> 16);
}
__device__ __forceinline__ float fast_tanh(float x) {
  float e = __expf(2.0f * x);                       // inf-safe: e=inf -> rcp=0 -> 1
  return 1.0f - 2.0f * __builtin_amdgcn_rcpf(e + 1.0f);
}

// ---- pack kernel: weights -> d_ws as bf16 B-fragments ----
// ws elems: [0,4096) Wrel1 | [4096,8192) Wroot1 | [8192,12288) Wrel2 |
//           [12288,16384) Wroot2 | [16384,17408) heads
__global__ void pack_weights(const float* __restrict__ Wrel1, const float* __restrict__ Wroot1,
                             const float* __restrict__ Wrel2, const float* __restrict__ Wroot2,
                             const float* __restrict__ Wheads, unsigned short* __restrict__ ws) {
  int id = blockIdx.x * 256 + threadIdx.x;
  if (id < 16384) {
    const float* W = (id < 4096) ? Wrel1 : (id < 8192) ? Wroot1 : (id < 12288) ? Wrel2 : Wroot2;
    int m = id & 4095;
    int e = m & 7, lane = (m >> 3) & 63, nt = (m >> 9) & 3, ks = m >> 11;
    int k = ((lane >> 4) << 3) + e + (ks << 5);
    int col = (nt << 4) + (lane & 15);
    ws[id] = f2bf(W[k * 64 + col]);
  } else if (id < 17408) {
    int m = id - 16384;
    int e = m & 7, lane = (m >> 3) & 63, ks = m >> 9;
    int k = ((lane >> 4) << 3) + e + (ks << 5);
    int c = lane & 15, j = c >> 1, o = c & 1;
    ws[id] = f2bf(Wheads[(j * 64 + k) * 2 + o]);
  }
}

__launch_bounds__(256, 4)
__global__ void actor_main(const float* __restrict__ x,
                           const float* __restrict__ Wj_g, const float* __restrict__ bj_g,
                           const float* __restrict__ Wt_g, const float* __restrict__ bt_g,
                           const float* __restrict__ brel1_g, const float* __restrict__ brel2_g,
                           const float* __restrict__ bh_g,
                           const unsigned short* __restrict__ wsw,
                           float* __restrict__ out) {
  __shared__ __align__(16) unsigned char smem[LDS_SZ];
  const int t = threadIdx.x;
  const int lane = t & 63;
  const int w = t >> 6;                 // wave id = N-tile (16 cols) for conv GEMMs
  const int gbase = blockIdx.x << 4;    // 16 graphs per block
  const int l15 = lane & 15;
  const int q = lane >> 4;
  const int ks16 = q << 4;              // A/B frag k-slice byte offset {0,16,32,48}
  const int relc = l15 + (w << 4);      // this wave's output column

  // ---- address precompute (layer-invariant) ----
  unsigned int aggA[9];                 // AGG A-frag gather addr per M-tile
#pragma unroll
  for (int m = 0; m < 9; m++) {
    int r = (m << 4) + l15;
    int g = (57 * r) >> 9;              // exact r/9 for r<144
    int node = r - 9 * g;
    int row = (node == 0) ? g : 9 * g;  // torso row uses S(g); joint rows use T(g)=H[9g]
    unsigned int base = (node == 0) ? (unsigned)LDS_S : 0u;
    aggA[m] = base + row * 128 + (ks16 ^ ((row & 7) << 4));
  }
  const unsigned int h0b = l15 * 128 + (ks16 ^ ((l15 & 7) << 4));  // H A-frag base (+m*2048)
  unsigned int wb[4];                   // tanh-write bases (+m*2048)
#pragma unroll
  for (int i = 0; i < 4; i++) {
    int rr = (q << 2) + i;
    wb[i] = rr * 128 + ((2 * relc) ^ ((rr & 7) << 4));
  }

  // ---- stage x (overlaid on W region) and heads frags ----
  {
    const float4* xg = reinterpret_cast<const float4*>(x + (size_t)gbase * 99);
    float4* xl4 = reinterpret_cast<float4*>(smem + LDS_W);
    xl4[t] = xg[t];                                  // 396 float4 per block
    if (t + 256 < 396) xl4[t + 256] = xg[t + 256];
    const bf16x8* hsrc = reinterpret_cast<const bf16x8*>(wsw + 16384);
    bf16x8* hdst = reinterpret_cast<bf16x8*>(smem + LDS_HW);
    if (t < 128) hdst[t] = hsrc[t];
  }
  // per-thread weight regs (thread's out-dim = lane for proj)
  float Wtr[11];
#pragma unroll
  for (int k = 0; k < 11; k++) Wtr[k] = Wt_g[k * 64 + lane];
  const float btr = bt_g[lane];
  const float Wj0 = Wj_g[lane], Wj1 = Wj_g[64 + lane], bjr = bj_g[lane];
  const float brelA = brel1_g[relc], brelB = brel2_g[relc];
  __syncthreads();

  // ---- input projection (VALU; x broadcast from LDS) ----
  const float* xl = reinterpret_cast<const float*>(smem + LDS_W);
#pragma unroll
  for (int it = 0; it < 4; it++) {                   // torso rows
    int g = w + (it << 2);
    float acc1 = btr;
#pragma unroll
    for (int k = 0; k < 11; k++) acc1 += xl[g * 99 + k] * Wtr[k];
    int row = 9 * g;
    *reinterpret_cast<unsigned short*>(smem + row * 128 + ((2 * lane) ^ ((row & 7) << 4))) =
        (unsigned short)cvtpk(acc1, acc1);
  }
#pragma unroll
  for (int it = 0; it < 32; it++) {                  // joint rows
    int jr = w + (it << 2);
    int g = jr >> 3, j = jr & 7;
    int xb = g * 99 + 11 + 11 * j;
    float acc1 = bjr + xl[xb] * Wj0 + xl[xb + 1] * Wj1;
    int row = 9 * g + 1 + j;
    *reinterpret_cast<unsigned short*>(smem + row * 128 + ((2 * lane) ^ ((row & 7) << 4))) =
        (unsigned short)cvtpk(acc1, acc1);
  }
  __syncthreads();

  // ---- stage layer-1 weights (x region now dead) ----
  {
    const bf16x8* wsrc = reinterpret_cast<const bf16x8*>(wsw);
    bf16x8* wdst = reinterpret_cast<bf16x8*>(smem + LDS_W);
#pragma unroll
    for (int i = 0; i < 4; i++) wdst[t + 256 * i] = wsrc[t + 256 * i];
  }

  f32x4 acc[9];
#pragma unroll
  for (int layer = 0; layer < 2; layer++) {
    const float brel = (layer == 0) ? brelA : brelB;

    // ---- S pass: S[g][d] = sum_j H[9g+1+j][d]; thread = (g = t>>4, 4 dims) ----
    {
      int gS = t >> 4, dq = t & 15;
      int rb = dq << 3;
      float s0 = 0.f, s1 = 0.f, s2 = 0.f, s3 = 0.f;
#pragma unroll
      for (int j = 0; j < 8; j++) {
        int row = 9 * gS + 1 + j;
        uint2 p = *reinterpret_cast<const uint2*>(smem + row * 128 + (rb ^ ((row & 7) << 4)));
        s0 += asf(p.x << 16); s1 += asf(p.x & 0xffff0000u);
        s2 += asf(p.y << 16); s3 += asf(p.y & 0xffff0000u);
      }
      uint2 o; o.x = cvtpk(s0, s1); o.y = cvtpk(s2, s3);
      *reinterpret_cast<uint2*>(smem + LDS_S + gS * 128 + (rb ^ ((gS & 7) << 4))) = o;
    }
    __syncthreads();   // S ready; W(layer) visible

    // ---- B-frags from LDS ----
    const unsigned char* wrel = smem + LDS_W;
    const unsigned char* wroot = smem + LDS_W + 8192;
    bf16x8 bRel0  = *reinterpret_cast<const bf16x8*>(wrel  + ((0 + w) * 64 + lane) * 16);
    bf16x8 bRel1  = *reinterpret_cast<const bf16x8*>(wrel  + ((4 + w) * 64 + lane) * 16);
    bf16x8 bRoot0 = *reinterpret_cast<const bf16x8*>(wroot + ((0 + w) * 64 + lane) * 16);
    bf16x8 bRoot1 = *reinterpret_cast<const bf16x8*>(wroot + ((4 + w) * 64 + lane) * 16);

    // ---- fused REL+ROOT GEMM: 9 M-tiles x 4 chained MFMA ----
#pragma unroll
    for (int m = 0; m < 9; m++) {
      const int off = m * 2048;
      bf16x8 ag0 = *reinterpret_cast<const bf16x8*>(smem + aggA[m]);
      bf16x8 ag1 = *reinterpret_cast<const bf16x8*>(smem + (aggA[m] ^ 64u));
      bf16x8 a0  = *reinterpret_cast<const bf16x8*>(smem + h0b + off);
      bf16x8 a1  = *reinterpret_cast<const bf16x8*>(smem + (h0b ^ 64u) + off);
      f32x4 c = {brel, brel, brel, brel};
      c = __builtin_amdgcn_mfma_f32_16x16x32_bf16(ag0, bRel0, c, 0, 0, 0);
      c = __builtin_amdgcn_mfma_f32_16x16x32_bf16(ag1, bRel1, c, 0, 0, 0);
      c = __builtin_amdgcn_mfma_f32_16x16x32_bf16(a0, bRoot0, c, 0, 0, 0);
      acc[m] = __builtin_amdgcn_mfma_f32_16x16x32_bf16(a1, bRoot1, c, 0, 0, 0);
    }
    __syncthreads();   // all H/S reads done -> safe to overwrite H

    if (layer == 0) {  // stage layer-2 weights (visible after next barrier)
      const bf16x8* wsrc2 = reinterpret_cast<const bf16x8*>(wsw + 8192);
      bf16x8* wdst = reinterpret_cast<bf16x8*>(smem + LDS_W);
#pragma unroll
      for (int i = 0; i < 4; i++) wdst[t + 256 * i] = wsrc2[t + 256 * i];
    }

    // ---- tanh + packed-cvt + write H in place (base + offset:m*2048) ----
#pragma unroll
    for (int m = 0; m < 9; m++) {
      const int off = m * 2048;
      float t0 = fast_tanh(acc[m][0]);
      float t1 = fast_tanh(acc[m][1]);
      float t2 = fast_tanh(acc[m][2]);
      float t3 = fast_tanh(acc[m][3]);
      unsigned int p0 = cvtpk(t0, t1);
      unsigned int p1 = cvtpk(t2, t3);
      *reinterpret_cast<unsigned short*>(smem + wb[0] + off) = (unsigned short)p0;
      *reinterpret_cast<unsigned short*>(smem + wb[1] + off) = (unsigned short)(p0 >> 16);
      *reinterpret_cast<unsigned short*>(smem + wb[2] + off) = (unsigned short)p1;
      *reinterpret_cast<unsigned short*>(smem + wb[3] + off) = (unsigned short)(p1 >> 16);
    }
    __syncthreads();
  }

  // ---- heads: packed B [64,16], cols=(j,o); predicated scatter + softplus ----
  {
    const unsigned char* hw = smem + LDS_HW;
    bf16x8 hb0 = *reinterpret_cast<const bf16x8*>(hw + lane * 16);
    bf16x8 hb1 = *reinterpret_cast<const bf16x8*>(hw + (64 + lane) * 16);
    int c = l15;
#pragma unroll
    for (int u = 0; u < 2; u++) {
      int tt = (w << 1) + u;
      int jr = (tt << 4) + l15;
      int arow = 9 * (jr >> 3) + 1 + (jr & 7);
      unsigned int ha = arow * 128 + (ks16 ^ ((arow & 7) << 4));
      bf16x8 a0 = *reinterpret_cast<const bf16x8*>(smem + ha);
      bf16x8 a1 = *reinterpret_cast<const bf16x8*>(smem + (ha ^ 64u));
      f32x4 z = {0.f, 0.f, 0.f, 0.f};
      z = __builtin_amdgcn_mfma_f32_16x16x32_bf16(a0, hb0, z, 0, 0, 0);
      z = __builtin_amdgcn_mfma_f32_16x16x32_bf16(a1, hb1, z, 0, 0, 0);
#pragma unroll
      for (int i = 0; i < 4; i++) {
        int r = (tt << 4) + (q << 2) + i;           // joint index of this D row
        int gg = r >> 3, j2 = r & 7;
        if (c == 2 * j2) {
          out[(size_t)(gbase + gg) * 8 + j2] = z[i] + bh_g[2 * j2];
        } else if (c == 2 * j2 + 1) {
          float zz = z[i] + bh_g[2 * j2 + 1] + SOFTPLUS_BIAS;
          float sp = (zz > 20.0f) ? zz : __logf(1.0f + __expf(zz));
          out[524288 + (size_t)(gbase + gg) * 8 + j2] = sp;
        }
      }
    }
  }
}

extern "C" void kernel_launch(void* const* d_in, const int* in_sizes, int n_in,
                              void* d_out, int out_size, void* d_ws, size_t ws_size,
                              hipStream_t stream) {
  const float* x      = (const float*)d_in[0];
  // d_in[1] = edge_index (star structure hardcoded)
  const float* Wj     = (const float*)d_in[2];
  const float* bj     = (const float*)d_in[3];
  const float* Wt     = (const float*)d_in[4];
  const float* bt     = (const float*)d_in[5];
  const float* Wrel1  = (const float*)d_in[6];
  const float* brel1  = (const float*)d_in[7];
  const float* Wroot1 = (const float*)d_in[8];
  const float* Wrel2  = (const float*)d_in[9];
  const float* brel2  = (const float*)d_in[10];
  const float* Wroot2 = (const float*)d_in[11];
  const float* Wheads = (const float*)d_in[12];
  const float* bh     = (const float*)d_in[13];
  unsigned short* ws16 = (unsigned short*)d_ws;
  float* out = (float*)d_out;

  hipLaunchKernelGGL(pack_weights, dim3(68), dim3(256), 0, stream,
                     Wrel1, Wroot1, Wrel2, Wroot2, Wheads, ws16);
  hipLaunchKernelGGL(actor_main, dim3(4096), dim3(256), 0, stream,
                     x, Wj, bj, Wt, bt, brel1, brel2, bh, ws16, out);
}